// Round 8
// baseline (180.447 us; speedup 1.0000x reference)
//
#include <hip/hip_runtime.h>

typedef _Float16 half_t;
typedef _Float16 half8 __attribute__((ext_vector_type(8)));
typedef _Float16 half4 __attribute__((ext_vector_type(4)));
typedef float floatx4 __attribute__((ext_vector_type(4)));
typedef float floatx16 __attribute__((ext_vector_type(16)));

#define C1 0.72134752044448170368f   /* 2*log2(e)/SCALE, SCALE=4 */
#define C2 14.4269504088896340736f   /* 10*log2(e) */
#define C3 28.8539008177792681472f   /* 20*log2(e) */

__device__ __forceinline__ floatx4 zero4() {
    floatx4 z; z[0] = z[1] = z[2] = z[3] = 0.f; return z;
}
__device__ __forceinline__ floatx16 zero16() {
    floatx16 z;
#pragma unroll
    for (int i = 0; i < 16; ++i) z[i] = 0.f;
    return z;
}

// p = exp(10*tanh(s)) = exp2(b - C3/(exp2(S')+1)),
// S' = 2*log2e*s (folded into Wq), b = C2 (unmasked) or -1e30 (masked -> p=0).
//
// TRANS-COUNT CUT, clean retry of round 4. Model (fits all 8 rounds):
// f32 transcendentals execute at ~16 cyc/wave64 on a dedicated pipe ->
// 3 trans/element = 41 us/SIMD occupancy floor; round-0's 48.3 us is 85%
// of it, and every scheduling lever (occupancy R1, VGPRs R2, SW pipeline
// R3, stage-split R6, sched_barrier fences R7) was null because the pipe
// is saturated. Only count reduction helps. v_rcp_f32 -> integer-magic
// seed + 2 Newton steps on the regular VALU (which has ~4x slack):
// rel err ~1.3e-6 -> p rel err C3*ln2*1.3e-6 ~ 2.6e-5, invisible under
// the existing fp16 P quantization. Round 4's version of this REGRESSED
// only because __launch_bounds__(64,8) capped VGPRs at 32 and the Newton
// temps spilled to scratch (WRITE_SIZE 10.5->21 MB). Here the cap is 128.
// Validity gates: WRITE_SIZE stays ~16.4 MB (no spill), VGPR ~44-64.
__device__ __forceinline__ float pfun(float sp, float b) {
    float u = __builtin_amdgcn_exp2f(sp);           // trans #1
    float w = u + 1.0f;                             // w in [1, ~1e13]
    float y = __int_as_float(0x7EF127EAu - (unsigned)__float_as_int(w));
    y = y * (2.0f - w * y);                         // Newton 1: ~1.2e-3
    y = y * (2.0f - w * y);                         // Newton 2: ~1.3e-6
    return __builtin_amdgcn_exp2f(__builtin_fmaf(-C3, y, b));   // trans #2
}

// ---------------- k0: convert weights to fp16 (Wq pre-scaled by C1) --------
__global__ void k_convw(const float* __restrict__ Wq, const float* __restrict__ Wk,
                        const float* __restrict__ Wv, const float* __restrict__ Wo,
                        half_t* __restrict__ Wh) {
    int idx = blockIdx.x * 256 + threadIdx.x;      // 0..65535
    int which = idx >> 14;
    int off = idx & 16383;
    const float* src = (which == 0) ? Wq : (which == 1) ? Wk : (which == 2) ? Wv : Wo;
    float scale = (which == 0) ? C1 : 1.0f;
    Wh[idx] = (half_t)(src[off] * scale);
}

// ---------------- k1: QKV projections -------------------------------------
// Q,K: operand-swapped (A=W, B=X) -> D[f][token], half4 stores into
//      layout (bc, h, n, 16).
// V:   original order (A=X, B=W) -> D[token][f], half4 stores into
//      TRANSPOSED layout (bc, h, d, n) consumed directly by attn's PV MFMA.
__global__ __launch_bounds__(256) void k_proj(
        const float* __restrict__ Q, const float* __restrict__ K,
        const float* __restrict__ V, const half_t* __restrict__ WhBase,
        half_t* __restrict__ qw, half_t* __restrict__ kw, half_t* __restrict__ vw) {
    int which = blockIdx.y;
    const float* X = (which == 0) ? Q : (which == 1) ? K : V;
    const half_t* W = WhBase + which * 16384;

    int tid = threadIdx.x;
    int w = tid >> 6, lane = tid & 63;
    int l15 = lane & 15, quad = lane >> 4;
    int tokbase = blockIdx.x * 64 + w * 16;

    floatx4 acc[8];
#pragma unroll
    for (int nt = 0; nt < 8; ++nt) acc[nt] = zero4();

#pragma unroll
    for (int ks = 0; ks < 4; ++ks) {
        const float* ap = X + (tokbase + l15) * 128 + ks * 32 + quad * 8;
        float4 a0 = *(const float4*)ap;
        float4 a1 = *(const float4*)(ap + 4);
        half8 xf;
        xf[0] = (half_t)a0.x; xf[1] = (half_t)a0.y; xf[2] = (half_t)a0.z; xf[3] = (half_t)a0.w;
        xf[4] = (half_t)a1.x; xf[5] = (half_t)a1.y; xf[6] = (half_t)a1.z; xf[7] = (half_t)a1.w;
        if (which == 2) {
#pragma unroll
            for (int nt = 0; nt < 8; ++nt) {
                half8 wf = *(const half8*)(W + (nt * 16 + l15) * 128 + ks * 32 + quad * 8);
                acc[nt] = __builtin_amdgcn_mfma_f32_16x16x32_f16(xf, wf, acc[nt], 0, 0, 0);
            }
        } else {
#pragma unroll
            for (int nt = 0; nt < 8; ++nt) {
                half8 wf = *(const half8*)(W + (nt * 16 + l15) * 128 + ks * 32 + quad * 8);
                acc[nt] = __builtin_amdgcn_mfma_f32_16x16x32_f16(wf, xf, acc[nt], 0, 0, 0);
            }
        }
    }

    if (which == 2) {
        // D[token = quad*4+r][f = l15]; transposed store (bc, h, d, n)
        int R0 = tokbase + quad * 4;
        int bc = R0 >> 9, n0 = R0 & 511;
#pragma unroll
        for (int nt = 0; nt < 8; ++nt) {
            half4 hv;
            hv[0] = (half_t)acc[nt][0]; hv[1] = (half_t)acc[nt][1];
            hv[2] = (half_t)acc[nt][2]; hv[3] = (half_t)acc[nt][3];
            *(half4*)(vw + ((bc * 8 + nt) * 16 + l15) * 512 + n0) = hv;
        }
    } else {
        // D[f = quad*4+r][token = l15]; store (bc, h, n, 16)
        int R = tokbase + l15;
        int bc = R >> 9, n = R & 511;
        half_t* Y = (which == 0) ? qw : kw;
#pragma unroll
        for (int nt = 0; nt < 8; ++nt) {
            half4 hv;
            hv[0] = (half_t)acc[nt][0]; hv[1] = (half_t)acc[nt][1];
            hv[2] = (half_t)acc[nt][2]; hv[3] = (half_t)acc[nt][3];
            *(half4*)(Y + ((bc * 8 + nt) * 512 + n) * 16 + quad * 4) = hv;
        }
    }
}

// ---------------- k2: fused attention + output projection ------------------
// grid 1024 = (bc, q-tile); 8 waves/block, wave = head. Round-5 structure
// (k_out fused: saved its ~14 us latency-bound kernel + aw round-trip),
// plain 16-iteration loop (R6/R7's stage-split/fences were null), with the
// trans-count-cut pfun above as the single change vs round 5.
__global__ __launch_bounds__(512, 4) void k_attn_out(
        const half_t* __restrict__ qg, const half_t* __restrict__ kg,
        const half_t* __restrict__ vTg, const int* __restrict__ mask,
        const half_t* __restrict__ Wo, float* __restrict__ out) {
    __shared__ float bias[512];
    __shared__ half_t Pb[8][32 * 36];        // per-wave P tile, row stride 36
    __shared__ half_t attO[32 * 136];        // [token_local][f], stride 136

    int bx = blockIdx.x;                     // 0..1023
    int bc = bx >> 4, qt = bx & 15;
    int tid = threadIdx.x;
    int w = tid >> 6, lane = tid & 63;
    int h = w;
    int bch = bc * 8 + h;
    int l31 = lane & 31, hf = lane >> 5;
    int l15 = lane & 15, quad = lane >> 4;

    const half_t* qh = qg + bch * 8192;
    const half_t* kh = kg + bch * 8192;
    const half_t* vh = vTg + bch * 8192;     // (d, n): d*512 + n

    bias[tid] = mask[bc * 512 + tid] ? -1.0e30f : C2;
    __syncthreads();

    int qbase = qt * 32;
    // Q B-fragment (32x32x16): lane holds q[qrow = l31][d = hf*8 + j]
    half8 qf = *(const half8*)(qh + (qbase + l31) * 16 + hf * 8);

    half8 ones;
#pragma unroll
    for (int j = 0; j < 8; ++j) ones[j] = (half_t)1.0f;

    floatx4 O[2], Os[2];
    O[0] = zero4(); O[1] = zero4();
    Os[0] = zero4(); Os[1] = zero4();
    const float4* b4 = (const float4*)bias;
    half_t* Pw = &Pb[w][0];

#pragma unroll 1
    for (int c = 0; c < 16; ++c) {
        // K A-fragment: A[key = c*32 + l31][d = hf*8 + j]
        half8 kf = *(const half8*)(kh + (c * 32 + l31) * 16 + hf * 8);
        // V^T A-fragment for PV: A[d = l15][key = c*32 + quad*8 + j]
        half8 vf = *(const half8*)(vh + l15 * 512 + c * 32 + quad * 8);
        float4 bv[4];
#pragma unroll
        for (int g = 0; g < 4; ++g) bv[g] = b4[c * 8 + hf + 2 * g];

        // S^T tile: D[key][qrow], key = 8*(r>>2) + 4*hf + (r&3), qrow-local = l31
        floatx16 S = __builtin_amdgcn_mfma_f32_32x32x16_f16(kf, qf, zero16(), 0, 0, 0);
#pragma unroll
        for (int g = 0; g < 4; ++g) {
            float p0 = pfun(S[4 * g + 0], bv[g].x);
            float p1 = pfun(S[4 * g + 1], bv[g].y);
            float p2 = pfun(S[4 * g + 2], bv[g].z);
            float p3 = pfun(S[4 * g + 3], bv[g].w);
            auto t0 = __builtin_amdgcn_cvt_pkrtz(p0, p1);   // __fp16 x2
            auto t1 = __builtin_amdgcn_cvt_pkrtz(p2, p3);
            half4 ph;
            ph[0] = (half_t)t0[0]; ph[1] = (half_t)t0[1];
            ph[2] = (half_t)t1[0]; ph[3] = (half_t)t1[1];
            *(half4*)(Pw + l31 * 36 + hf * 4 + g * 8) = ph;
        }
        // O^T += V^T * P^T ; Os += ones * P^T (row sums on MFMA pipe)
#pragma unroll
        for (int nt2 = 0; nt2 < 2; ++nt2) {
            half8 pb = *(const half8*)(Pw + (nt2 * 16 + l15) * 36 + quad * 8);
            O[nt2]  = __builtin_amdgcn_mfma_f32_16x16x32_f16(vf,   pb, O[nt2],  0, 0, 0);
            Os[nt2] = __builtin_amdgcn_mfma_f32_16x16x32_f16(ones, pb, Os[nt2], 0, 0, 0);
        }
    }

    // Normalize (lane-local: Os rows replicate the rowsum; O col = q = l15)
    // and write this head's 32x16 tile into attO[token_local][h*16 + ...].
#pragma unroll
    for (int nt = 0; nt < 2; ++nt) {
        float iv = __builtin_amdgcn_rcpf(Os[nt][0]);
        int qrl = nt * 16 + l15;             // token_local
        half4 ov;
        ov[0] = (half_t)(O[nt][0] * iv);
        ov[1] = (half_t)(O[nt][1] * iv);
        ov[2] = (half_t)(O[nt][2] * iv);
        ov[3] = (half_t)(O[nt][3] * iv);
        *(half4*)(attO + qrl * 136 + h * 16 + quad * 4) = ov;
    }
    __syncthreads();

    // ---- output projection: out[32 tokens][128 f] = attO @ Wo^T ----
    // wave w: tokens [tw*16, tw*16+16), f [fw*32, fw*32+32); 8 MFMAs.
    int tw = w & 1, fw = w >> 1;
    const half_t* xbase = attO + (tw * 16 + l15) * 136;
    floatx4 acc2[2];
    acc2[0] = zero4(); acc2[1] = zero4();
#pragma unroll
    for (int ks = 0; ks < 4; ++ks) {
        half8 xf = *(const half8*)(xbase + ks * 32 + quad * 8);
#pragma unroll
        for (int nt = 0; nt < 2; ++nt) {
            half8 wf = *(const half8*)(Wo + (fw * 32 + nt * 16 + l15) * 128 + ks * 32 + quad * 8);
            acc2[nt] = __builtin_amdgcn_mfma_f32_16x16x32_f16(wf, xf, acc2[nt], 0, 0, 0);
        }
    }
    // D[f = fw*32 + nt*16 + quad*4 + r][token = l15] -> coalesced float4
    int tokg = bc * 512 + qt * 32 + tw * 16 + l15;
#pragma unroll
    for (int nt = 0; nt < 2; ++nt) {
        float4 o;
        o.x = acc2[nt][0]; o.y = acc2[nt][1]; o.z = acc2[nt][2]; o.w = acc2[nt][3];
        *(float4*)(out + tokg * 128 + fw * 32 + nt * 16 + quad * 4) = o;
    }
}

extern "C" void kernel_launch(void* const* d_in, const int* in_sizes, int n_in,
                              void* d_out, int out_size, void* d_ws, size_t ws_size,
                              hipStream_t stream) {
    const float* Q    = (const float*)d_in[0];
    const float* K    = (const float*)d_in[1];
    const float* V    = (const float*)d_in[2];
    const int*   mask = (const int*)d_in[3];
    const float* Wq   = (const float*)d_in[4];
    const float* Wk   = (const float*)d_in[5];
    const float* Wv   = (const float*)d_in[6];
    const float* Wo   = (const float*)d_in[7];
    float* out = (float*)d_out;

    half_t* ws = (half_t*)d_ws;
    half_t* Wh = ws;                       // 65536 halves (4 x 128x128)
    half_t* qw = ws + 65536;               // each 4194304 halves
    half_t* kw = qw + 4194304;
    half_t* vw = kw + 4194304;             // transposed (bc,h,d,n)

    k_convw<<<256, 256, 0, stream>>>(Wq, Wk, Wv, Wo, Wh);
    k_proj<<<dim3(512, 3), 256, 0, stream>>>(Q, K, V, Wh, qw, kw, vw);
    k_attn_out<<<1024, 512, 0, stream>>>(qw, kw, vw, mask, Wh + 49152, out);
}

// Round 10
// 173.982 us; speedup vs baseline: 1.0372x; 1.0372x over previous
//
#include <hip/hip_runtime.h>

typedef _Float16 half_t;
typedef _Float16 half8 __attribute__((ext_vector_type(8)));
typedef _Float16 half4 __attribute__((ext_vector_type(4)));
typedef float floatx4 __attribute__((ext_vector_type(4)));
typedef float floatx16 __attribute__((ext_vector_type(16)));

#define C1 0.72134752044448170368f   /* 2*log2(e)/SCALE, SCALE=4 */
#define C2 14.4269504088896340736f   /* 10*log2(e) */
#define C3 28.8539008177792681472f   /* 20*log2(e) */

__device__ __forceinline__ floatx4 zero4() {
    floatx4 z; z[0] = z[1] = z[2] = z[3] = 0.f; return z;
}
__device__ __forceinline__ floatx16 zero16() {
    floatx16 z;
#pragma unroll
    for (int i = 0; i < 16; ++i) z[i] = 0.f;
    return z;
}

// p = exp(10*tanh(s)) computed as exp2(b - C3 * rcp(exp2(S') + 1)),
// S' = 2*log2e*s (folded into Wq), b = C2 (unmasked) or -1e30 (masked -> p=0).
// R4/R8 both proved replacing v_rcp_f32 with Newton iterations regresses
// (R8 ran spill-free at VGPR=40: VALU busy 31->42 us) -- the hardware rcp's
// ~8 issue cycles beat 5 replacement VALU ops. This op mix is the floor.
__device__ __forceinline__ float pfun(float sp, float b) {
    float u = __builtin_amdgcn_exp2f(sp);
    float r = __builtin_amdgcn_rcpf(u + 1.0f);
    return __builtin_amdgcn_exp2f(b - C3 * r);
}

// ---------------- k0: convert weights to fp16 (Wq pre-scaled by C1) --------
__global__ void k_convw(const float* __restrict__ Wq, const float* __restrict__ Wk,
                        const float* __restrict__ Wv, const float* __restrict__ Wo,
                        half_t* __restrict__ Wh) {
    int idx = blockIdx.x * 256 + threadIdx.x;      // 0..65535
    int which = idx >> 14;
    int off = idx & 16383;
    const float* src = (which == 0) ? Wq : (which == 1) ? Wk : (which == 2) ? Wv : Wo;
    float scale = (which == 0) ? C1 : 1.0f;
    Wh[idx] = (half_t)(src[off] * scale);
}

// ---------------- k1: QKV projections -------------------------------------
// Q,K: operand-swapped (A=W, B=X) -> D[f][token], half4 stores into
//      layout (bc, h, n, 16).
// V:   original order (A=X, B=W) -> D[token][f], half4 stores into
//      TRANSPOSED layout (bc, h, d, n) consumed directly by attn's PV MFMA.
__global__ __launch_bounds__(256) void k_proj(
        const float* __restrict__ Q, const float* __restrict__ K,
        const float* __restrict__ V, const half_t* __restrict__ WhBase,
        half_t* __restrict__ qw, half_t* __restrict__ kw, half_t* __restrict__ vw) {
    int which = blockIdx.y;
    const float* X = (which == 0) ? Q : (which == 1) ? K : V;
    const half_t* W = WhBase + which * 16384;

    int tid = threadIdx.x;
    int w = tid >> 6, lane = tid & 63;
    int l15 = lane & 15, quad = lane >> 4;
    int tokbase = blockIdx.x * 64 + w * 16;

    floatx4 acc[8];
#pragma unroll
    for (int nt = 0; nt < 8; ++nt) acc[nt] = zero4();

#pragma unroll
    for (int ks = 0; ks < 4; ++ks) {
        const float* ap = X + (tokbase + l15) * 128 + ks * 32 + quad * 8;
        float4 a0 = *(const float4*)ap;
        float4 a1 = *(const float4*)(ap + 4);
        half8 xf;
        xf[0] = (half_t)a0.x; xf[1] = (half_t)a0.y; xf[2] = (half_t)a0.z; xf[3] = (half_t)a0.w;
        xf[4] = (half_t)a1.x; xf[5] = (half_t)a1.y; xf[6] = (half_t)a1.z; xf[7] = (half_t)a1.w;
        if (which == 2) {
#pragma unroll
            for (int nt = 0; nt < 8; ++nt) {
                half8 wf = *(const half8*)(W + (nt * 16 + l15) * 128 + ks * 32 + quad * 8);
                acc[nt] = __builtin_amdgcn_mfma_f32_16x16x32_f16(xf, wf, acc[nt], 0, 0, 0);
            }
        } else {
#pragma unroll
            for (int nt = 0; nt < 8; ++nt) {
                half8 wf = *(const half8*)(W + (nt * 16 + l15) * 128 + ks * 32 + quad * 8);
                acc[nt] = __builtin_amdgcn_mfma_f32_16x16x32_f16(wf, xf, acc[nt], 0, 0, 0);
            }
        }
    }

    if (which == 2) {
        // D[token = quad*4+r][f = l15]; transposed store (bc, h, d, n)
        int R0 = tokbase + quad * 4;
        int bc = R0 >> 9, n0 = R0 & 511;
#pragma unroll
        for (int nt = 0; nt < 8; ++nt) {
            half4 hv;
            hv[0] = (half_t)acc[nt][0]; hv[1] = (half_t)acc[nt][1];
            hv[2] = (half_t)acc[nt][2]; hv[3] = (half_t)acc[nt][3];
            *(half4*)(vw + ((bc * 8 + nt) * 16 + l15) * 512 + n0) = hv;
        }
    } else {
        // D[f = quad*4+r][token = l15]; store (bc, h, n, 16)
        int R = tokbase + l15;
        int bc = R >> 9, n = R & 511;
        half_t* Y = (which == 0) ? qw : kw;
#pragma unroll
        for (int nt = 0; nt < 8; ++nt) {
            half4 hv;
            hv[0] = (half_t)acc[nt][0]; hv[1] = (half_t)acc[nt][1];
            hv[2] = (half_t)acc[nt][2]; hv[3] = (half_t)acc[nt][3];
            *(half4*)(Y + ((bc * 8 + nt) * 512 + n) * 16 + quad * 4) = hv;
        }
    }
}

// ---------------- k2: fused attention + output projection ------------------
// grid 1024 = (bc, q-tile); 8 waves/block, wave = head. Round-5 structure
// (k_out fused: that deletion was the net win) with ONE change: an LDS pad
// caps residency at 2 blocks/CU = 16 waves/CU.
// Rationale: same per-wave code measured 48.3 us at 16 waves/CU (R0,
// 1-wave blocks), 54.1 at 32 waves (R1), 57.8 at 32 waves (R5, +out-proj
// tail). Against the saturated trans/VALU pipes, extra resident waves add
// only queueing/LDS/L1 interference (~6 us). This restores R0's wave count
// inside the fused kernel. Zero math/schedule change -- pure co-residency
// experiment. Expected: attn 57.8 -> ~50-53; null => penalty is structural.
// (Round-9 run of this exact kernel died to container-acquisition infra
// failure before dispatch; resubmitted unchanged.)
__global__ __launch_bounds__(512, 4) void k_attn_out(
        const half_t* __restrict__ qg, const half_t* __restrict__ kg,
        const half_t* __restrict__ vTg, const int* __restrict__ mask,
        const half_t* __restrict__ Wo, float* __restrict__ out) {
    __shared__ float bias[512];
    __shared__ half_t Pb[8][32 * 36];        // per-wave P tile, row stride 36
    __shared__ half_t attO[32 * 136];        // [token_local][f], stride 136
    __shared__ char occ_pad[28672];          // pushes LDS to ~56.5 KB -> 2 blocks/CU

    int bx = blockIdx.x;                     // 0..1023
    int bc = bx >> 4, qt = bx & 15;
    int tid = threadIdx.x;
    int w = tid >> 6, lane = tid & 63;
    int h = w;
    int bch = bc * 8 + h;
    int l31 = lane & 31, hf = lane >> 5;
    int l15 = lane & 15, quad = lane >> 4;

    // keep the pad live (one volatile byte per wave; compiler cannot elide)
    if (lane == 0) *(volatile char*)&occ_pad[w] = 0;

    const half_t* qh = qg + bch * 8192;
    const half_t* kh = kg + bch * 8192;
    const half_t* vh = vTg + bch * 8192;     // (d, n): d*512 + n

    bias[tid] = mask[bc * 512 + tid] ? -1.0e30f : C2;
    __syncthreads();

    int qbase = qt * 32;
    // Q B-fragment (32x32x16): lane holds q[qrow = l31][d = hf*8 + j]
    half8 qf = *(const half8*)(qh + (qbase + l31) * 16 + hf * 8);

    half8 ones;
#pragma unroll
    for (int j = 0; j < 8; ++j) ones[j] = (half_t)1.0f;

    floatx4 O[2], Os[2];
    O[0] = zero4(); O[1] = zero4();
    Os[0] = zero4(); Os[1] = zero4();
    const float4* b4 = (const float4*)bias;
    half_t* Pw = &Pb[w][0];

#pragma unroll 1
    for (int c = 0; c < 16; ++c) {
        // K A-fragment: A[key = c*32 + l31][d = hf*8 + j]
        half8 kf = *(const half8*)(kh + (c * 32 + l31) * 16 + hf * 8);
        // V^T A-fragment for PV: A[d = l15][key = c*32 + quad*8 + j]
        half8 vf = *(const half8*)(vh + l15 * 512 + c * 32 + quad * 8);
        float4 bv[4];
#pragma unroll
        for (int g = 0; g < 4; ++g) bv[g] = b4[c * 8 + hf + 2 * g];

        // S^T tile: D[key][qrow], key = 8*(r>>2) + 4*hf + (r&3), qrow-local = l31
        floatx16 S = __builtin_amdgcn_mfma_f32_32x32x16_f16(kf, qf, zero16(), 0, 0, 0);
#pragma unroll
        for (int g = 0; g < 4; ++g) {
            float p0 = pfun(S[4 * g + 0], bv[g].x);
            float p1 = pfun(S[4 * g + 1], bv[g].y);
            float p2 = pfun(S[4 * g + 2], bv[g].z);
            float p3 = pfun(S[4 * g + 3], bv[g].w);
            auto t0 = __builtin_amdgcn_cvt_pkrtz(p0, p1);   // __fp16 x2
            auto t1 = __builtin_amdgcn_cvt_pkrtz(p2, p3);
            half4 ph;
            ph[0] = (half_t)t0[0]; ph[1] = (half_t)t0[1];
            ph[2] = (half_t)t1[0]; ph[3] = (half_t)t1[1];
            *(half4*)(Pw + l31 * 36 + hf * 4 + g * 8) = ph;
        }
        // O^T += V^T * P^T ; Os += ones * P^T (row sums on MFMA pipe)
#pragma unroll
        for (int nt2 = 0; nt2 < 2; ++nt2) {
            half8 pb = *(const half8*)(Pw + (nt2 * 16 + l15) * 36 + quad * 8);
            O[nt2]  = __builtin_amdgcn_mfma_f32_16x16x32_f16(vf,   pb, O[nt2],  0, 0, 0);
            Os[nt2] = __builtin_amdgcn_mfma_f32_16x16x32_f16(ones, pb, Os[nt2], 0, 0, 0);
        }
    }

    // Normalize (lane-local: Os rows replicate the rowsum; O col = q = l15)
    // and write this head's 32x16 tile into attO[token_local][h*16 + ...].
#pragma unroll
    for (int nt = 0; nt < 2; ++nt) {
        float iv = __builtin_amdgcn_rcpf(Os[nt][0]);
        int qrl = nt * 16 + l15;             // token_local
        half4 ov;
        ov[0] = (half_t)(O[nt][0] * iv);
        ov[1] = (half_t)(O[nt][1] * iv);
        ov[2] = (half_t)(O[nt][2] * iv);
        ov[3] = (half_t)(O[nt][3] * iv);
        *(half4*)(attO + qrl * 136 + h * 16 + quad * 4) = ov;
    }
    __syncthreads();

    // ---- output projection: out[32 tokens][128 f] = attO @ Wo^T ----
    // wave w: tokens [tw*16, tw*16+16), f [fw*32, fw*32+32); 8 MFMAs.
    int tw = w & 1, fw = w >> 1;
    const half_t* xbase = attO + (tw * 16 + l15) * 136;
    floatx4 acc2[2];
    acc2[0] = zero4(); acc2[1] = zero4();
#pragma unroll
    for (int ks = 0; ks < 4; ++ks) {
        half8 xf = *(const half8*)(xbase + ks * 32 + quad * 8);
#pragma unroll
        for (int nt = 0; nt < 2; ++nt) {
            half8 wf = *(const half8*)(Wo + (fw * 32 + nt * 16 + l15) * 128 + ks * 32 + quad * 8);
            acc2[nt] = __builtin_amdgcn_mfma_f32_16x16x32_f16(wf, xf, acc2[nt], 0, 0, 0);
        }
    }
    // D[f = fw*32 + nt*16 + quad*4 + r][token = l15] -> coalesced float4
    int tokg = bc * 512 + qt * 32 + tw * 16 + l15;
#pragma unroll
    for (int nt = 0; nt < 2; ++nt) {
        float4 o;
        o.x = acc2[nt][0]; o.y = acc2[nt][1]; o.z = acc2[nt][2]; o.w = acc2[nt][3];
        *(float4*)(out + tokg * 128 + fw * 32 + nt * 16 + quad * 4) = o;
    }
}

extern "C" void kernel_launch(void* const* d_in, const int* in_sizes, int n_in,
                              void* d_out, int out_size, void* d_ws, size_t ws_size,
                              hipStream_t stream) {
    const float* Q    = (const float*)d_in[0];
    const float* K    = (const float*)d_in[1];
    const float* V    = (const float*)d_in[2];
    const int*   mask = (const int*)d_in[3];
    const float* Wq   = (const float*)d_in[4];
    const float* Wk   = (const float*)d_in[5];
    const float* Wv   = (const float*)d_in[6];
    const float* Wo   = (const float*)d_in[7];
    float* out = (float*)d_out;

    half_t* ws = (half_t*)d_ws;
    half_t* Wh = ws;                       // 65536 halves (4 x 128x128)
    half_t* qw = ws + 65536;               // each 4194304 halves
    half_t* kw = qw + 4194304;
    half_t* vw = kw + 4194304;             // transposed (bc,h,d,n)

    k_convw<<<256, 256, 0, stream>>>(Wq, Wk, Wv, Wo, Wh);
    k_proj<<<dim3(512, 3), 256, 0, stream>>>(Q, K, V, Wh, qw, kw, vw);
    k_attn_out<<<1024, 512, 0, stream>>>(qw, kw, vw, mask, Wh + 49152, out);
}

// Round 11
// 160.120 us; speedup vs baseline: 1.1269x; 1.0866x over previous
//
#include <hip/hip_runtime.h>

typedef _Float16 half_t;
typedef _Float16 half8 __attribute__((ext_vector_type(8)));
typedef _Float16 half4 __attribute__((ext_vector_type(4)));
typedef float floatx4 __attribute__((ext_vector_type(4)));
typedef float floatx16 __attribute__((ext_vector_type(16)));

#define C1 0.72134752044448170368f   /* 2*log2(e)/SCALE, SCALE=4 */
#define C2 14.4269504088896340736f   /* 10*log2(e) */
#define C3 28.8539008177792681472f   /* 20*log2(e) */

__device__ __forceinline__ floatx4 zero4() {
    floatx4 z; z[0] = z[1] = z[2] = z[3] = 0.f; return z;
}
__device__ __forceinline__ floatx16 zero16() {
    floatx16 z;
#pragma unroll
    for (int i = 0; i < 16; ++i) z[i] = 0.f;
    return z;
}

// p = exp(10*tanh(s)) computed as exp2(b - C3 * rcp(exp2(S') + 1)),
// S' = 2*log2e*s (folded into Wq), b = C2 (unmasked) or -1e30 (masked -> p=0).
// Validated issue-port model (fits R8 to 0.3%): trans ~8 issue cyc, VALU ~2.
// This 3-trans + 2-VALU mix is the proven floor (R4/R8 both directions).
__device__ __forceinline__ float pfun(float sp, float b) {
    float u = __builtin_amdgcn_exp2f(sp);
    float r = __builtin_amdgcn_rcpf(u + 1.0f);
    return __builtin_amdgcn_exp2f(b - C3 * r);
}

// ---------------- k1: QKV projections + in-kernel weight conversion --------
// The separate k_convw launch is deleted (remainder accounting across 11
// runs: each launch costs ~5-10 us of serial overhead). Each proj block
// converts its own 128x128 fp32 weight panel into LDS (scaled by C1 for Wq),
// padded to stride 136 halves so the MFMA-loop ds_read_b128 at row-stride
// (which would be 16-way bank-conflicted at stride 128) becomes 2-way (free).
// A 4th grid slice (which==3, first 64 blocks) converts Wo to global halves
// for k_attn_out -- no extra launch, stream order guarantees completion.
// Q,K: operand-swapped (A=W, B=X) -> D[f][token] -> layout (bc, h, n, 16).
// V:   original order -> D[token][f] -> TRANSPOSED layout (bc, h, d, n).
__global__ __launch_bounds__(256) void k_proj(
        const float* __restrict__ Q, const float* __restrict__ K,
        const float* __restrict__ V,
        const float* __restrict__ Wq, const float* __restrict__ Wk,
        const float* __restrict__ Wv, const float* __restrict__ Wo,
        half_t* __restrict__ qw, half_t* __restrict__ kw, half_t* __restrict__ vw,
        half_t* __restrict__ Who) {
    int which = blockIdx.y;
    int tid = threadIdx.x;

    if (which == 3) {
        // Wo fp32 -> fp16, 64 active blocks x 256 threads = 16384 elems
        int bx = blockIdx.x;
        if (bx < 64) {
            int idx = bx * 256 + tid;
            Who[idx] = (half_t)Wo[idx];
        }
        return;
    }

    __shared__ half_t Wl[128 * 136];         // padded [f][e] panel, 34.8 KB

    const float* X    = (which == 0) ? Q  : (which == 1) ? K  : V;
    const float* Wsrc = (which == 0) ? Wq : (which == 1) ? Wk : Wv;
    float scale = (which == 0) ? C1 : 1.0f;

    // convert 16384 f32 -> fp16 into padded LDS; coalesced float4 loads,
    // half4 LDS writes (2-way bank alias only).
#pragma unroll
    for (int i = 0; i < 16; ++i) {
        int gidx = i * 1024 + tid * 4;
        float4 v = *(const float4*)(Wsrc + gidx);
        int f = gidx >> 7, e = gidx & 127;
        half4 hv;
        hv[0] = (half_t)(v.x * scale); hv[1] = (half_t)(v.y * scale);
        hv[2] = (half_t)(v.z * scale); hv[3] = (half_t)(v.w * scale);
        *(half4*)(Wl + f * 136 + e) = hv;
    }
    __syncthreads();

    int w = tid >> 6, lane = tid & 63;
    int l15 = lane & 15, quad = lane >> 4;
    int tokbase = blockIdx.x * 64 + w * 16;

    floatx4 acc[8];
#pragma unroll
    for (int nt = 0; nt < 8; ++nt) acc[nt] = zero4();

#pragma unroll
    for (int ks = 0; ks < 4; ++ks) {
        const float* ap = X + (tokbase + l15) * 128 + ks * 32 + quad * 8;
        float4 a0 = *(const float4*)ap;
        float4 a1 = *(const float4*)(ap + 4);
        half8 xf;
        xf[0] = (half_t)a0.x; xf[1] = (half_t)a0.y; xf[2] = (half_t)a0.z; xf[3] = (half_t)a0.w;
        xf[4] = (half_t)a1.x; xf[5] = (half_t)a1.y; xf[6] = (half_t)a1.z; xf[7] = (half_t)a1.w;
        if (which == 2) {
#pragma unroll
            for (int nt = 0; nt < 8; ++nt) {
                half8 wf = *(const half8*)(Wl + (nt * 16 + l15) * 136 + ks * 32 + quad * 8);
                acc[nt] = __builtin_amdgcn_mfma_f32_16x16x32_f16(xf, wf, acc[nt], 0, 0, 0);
            }
        } else {
#pragma unroll
            for (int nt = 0; nt < 8; ++nt) {
                half8 wf = *(const half8*)(Wl + (nt * 16 + l15) * 136 + ks * 32 + quad * 8);
                acc[nt] = __builtin_amdgcn_mfma_f32_16x16x32_f16(wf, xf, acc[nt], 0, 0, 0);
            }
        }
    }

    if (which == 2) {
        // D[token = quad*4+r][f = l15]; transposed store (bc, h, d, n)
        int R0 = tokbase + quad * 4;
        int bc = R0 >> 9, n0 = R0 & 511;
#pragma unroll
        for (int nt = 0; nt < 8; ++nt) {
            half4 hv;
            hv[0] = (half_t)acc[nt][0]; hv[1] = (half_t)acc[nt][1];
            hv[2] = (half_t)acc[nt][2]; hv[3] = (half_t)acc[nt][3];
            *(half4*)(vw + ((bc * 8 + nt) * 16 + l15) * 512 + n0) = hv;
        }
    } else {
        // D[f = quad*4+r][token = l15]; store (bc, h, n, 16)
        int R = tokbase + l15;
        int bc = R >> 9, n = R & 511;
        half_t* Y = (which == 0) ? qw : kw;
#pragma unroll
        for (int nt = 0; nt < 8; ++nt) {
            half4 hv;
            hv[0] = (half_t)acc[nt][0]; hv[1] = (half_t)acc[nt][1];
            hv[2] = (half_t)acc[nt][2]; hv[3] = (half_t)acc[nt][3];
            *(half4*)(Y + ((bc * 8 + nt) * 512 + n) * 16 + quad * 4) = hv;
        }
    }
}

// ---------------- k2: fused attention + output projection ------------------
// Exact round-5 configuration (best measured, 57.1-57.8 us): grid 1024 =
// (bc, q-tile), 8 waves/block, wave = head; out-projection after one
// barrier. R10 proved co-residency (16 vs 32 waves/CU) is null; the kernel
// sits at the validated VALU-issue-port floor (demand ~8850 cyc/wave,
// trans-dominated, op-mix proven irreducible in R4/R8).
__global__ __launch_bounds__(512, 4) void k_attn_out(
        const half_t* __restrict__ qg, const half_t* __restrict__ kg,
        const half_t* __restrict__ vTg, const int* __restrict__ mask,
        const half_t* __restrict__ Wo, float* __restrict__ out) {
    __shared__ float bias[512];
    __shared__ half_t Pb[8][32 * 36];        // per-wave P tile, row stride 36
    __shared__ half_t attO[32 * 136];        // [token_local][f], stride 136

    int bx = blockIdx.x;                     // 0..1023
    int bc = bx >> 4, qt = bx & 15;
    int tid = threadIdx.x;
    int w = tid >> 6, lane = tid & 63;
    int h = w;
    int bch = bc * 8 + h;
    int l31 = lane & 31, hf = lane >> 5;
    int l15 = lane & 15, quad = lane >> 4;

    const half_t* qh = qg + bch * 8192;
    const half_t* kh = kg + bch * 8192;
    const half_t* vh = vTg + bch * 8192;     // (d, n): d*512 + n

    bias[tid] = mask[bc * 512 + tid] ? -1.0e30f : C2;
    __syncthreads();

    int qbase = qt * 32;
    // Q B-fragment (32x32x16): lane holds q[qrow = l31][d = hf*8 + j]
    half8 qf = *(const half8*)(qh + (qbase + l31) * 16 + hf * 8);

    half8 ones;
#pragma unroll
    for (int j = 0; j < 8; ++j) ones[j] = (half_t)1.0f;

    floatx4 O[2], Os[2];
    O[0] = zero4(); O[1] = zero4();
    Os[0] = zero4(); Os[1] = zero4();
    const float4* b4 = (const float4*)bias;
    half_t* Pw = &Pb[w][0];

#pragma unroll 1
    for (int c = 0; c < 16; ++c) {
        // K A-fragment: A[key = c*32 + l31][d = hf*8 + j]
        half8 kf = *(const half8*)(kh + (c * 32 + l31) * 16 + hf * 8);
        // V^T A-fragment for PV: A[d = l15][key = c*32 + quad*8 + j]
        half8 vf = *(const half8*)(vh + l15 * 512 + c * 32 + quad * 8);
        float4 bv[4];
#pragma unroll
        for (int g = 0; g < 4; ++g) bv[g] = b4[c * 8 + hf + 2 * g];

        // S^T tile: D[key][qrow], key = 8*(r>>2) + 4*hf + (r&3), qrow-local = l31
        floatx16 S = __builtin_amdgcn_mfma_f32_32x32x16_f16(kf, qf, zero16(), 0, 0, 0);
#pragma unroll
        for (int g = 0; g < 4; ++g) {
            float p0 = pfun(S[4 * g + 0], bv[g].x);
            float p1 = pfun(S[4 * g + 1], bv[g].y);
            float p2 = pfun(S[4 * g + 2], bv[g].z);
            float p3 = pfun(S[4 * g + 3], bv[g].w);
            auto t0 = __builtin_amdgcn_cvt_pkrtz(p0, p1);   // __fp16 x2
            auto t1 = __builtin_amdgcn_cvt_pkrtz(p2, p3);
            half4 ph;
            ph[0] = (half_t)t0[0]; ph[1] = (half_t)t0[1];
            ph[2] = (half_t)t1[0]; ph[3] = (half_t)t1[1];
            *(half4*)(Pw + l31 * 36 + hf * 4 + g * 8) = ph;
        }
        // O^T += V^T * P^T ; Os += ones * P^T (row sums on MFMA pipe)
#pragma unroll
        for (int nt2 = 0; nt2 < 2; ++nt2) {
            half8 pb = *(const half8*)(Pw + (nt2 * 16 + l15) * 36 + quad * 8);
            O[nt2]  = __builtin_amdgcn_mfma_f32_16x16x32_f16(vf,   pb, O[nt2],  0, 0, 0);
            Os[nt2] = __builtin_amdgcn_mfma_f32_16x16x32_f16(ones, pb, Os[nt2], 0, 0, 0);
        }
    }

    // Normalize (lane-local: Os rows replicate the rowsum; O col = q = l15)
    // and write this head's 32x16 tile into attO[token_local][h*16 + ...].
#pragma unroll
    for (int nt = 0; nt < 2; ++nt) {
        float iv = __builtin_amdgcn_rcpf(Os[nt][0]);
        int qrl = nt * 16 + l15;             // token_local
        half4 ov;
        ov[0] = (half_t)(O[nt][0] * iv);
        ov[1] = (half_t)(O[nt][1] * iv);
        ov[2] = (half_t)(O[nt][2] * iv);
        ov[3] = (half_t)(O[nt][3] * iv);
        *(half4*)(attO + qrl * 136 + h * 16 + quad * 4) = ov;
    }
    __syncthreads();

    // ---- output projection: out[32 tokens][128 f] = attO @ Wo^T ----
    // wave w: tokens [tw*16, tw*16+16), f [fw*32, fw*32+32); 8 MFMAs.
    int tw = w & 1, fw = w >> 1;
    const half_t* xbase = attO + (tw * 16 + l15) * 136;
    floatx4 acc2[2];
    acc2[0] = zero4(); acc2[1] = zero4();
#pragma unroll
    for (int ks = 0; ks < 4; ++ks) {
        half8 xf = *(const half8*)(xbase + ks * 32 + quad * 8);
#pragma unroll
        for (int nt = 0; nt < 2; ++nt) {
            half8 wf = *(const half8*)(Wo + (fw * 32 + nt * 16 + l15) * 128 + ks * 32 + quad * 8);
            acc2[nt] = __builtin_amdgcn_mfma_f32_16x16x32_f16(wf, xf, acc2[nt], 0, 0, 0);
        }
    }
    // D[f = fw*32 + nt*16 + quad*4 + r][token = l15] -> coalesced float4
    int tokg = bc * 512 + qt * 32 + tw * 16 + l15;
#pragma unroll
    for (int nt = 0; nt < 2; ++nt) {
        float4 o;
        o.x = acc2[nt][0]; o.y = acc2[nt][1]; o.z = acc2[nt][2]; o.w = acc2[nt][3];
        *(float4*)(out + tokg * 128 + fw * 32 + nt * 16 + quad * 4) = o;
    }
}

extern "C" void kernel_launch(void* const* d_in, const int* in_sizes, int n_in,
                              void* d_out, int out_size, void* d_ws, size_t ws_size,
                              hipStream_t stream) {
    const float* Q    = (const float*)d_in[0];
    const float* K    = (const float*)d_in[1];
    const float* V    = (const float*)d_in[2];
    const int*   mask = (const int*)d_in[3];
    const float* Wq   = (const float*)d_in[4];
    const float* Wk   = (const float*)d_in[5];
    const float* Wv   = (const float*)d_in[6];
    const float* Wo   = (const float*)d_in[7];
    float* out = (float*)d_out;

    half_t* ws = (half_t*)d_ws;
    half_t* Who = ws + 49152;              // Wo fp16 (16384 halves)
    half_t* qw  = ws + 65536;              // each 4194304 halves
    half_t* kw  = qw + 4194304;
    half_t* vw  = kw + 4194304;            // transposed (bc,h,d,n)

    k_proj<<<dim3(512, 4), 256, 0, stream>>>(Q, K, V, Wq, Wk, Wv, Wo,
                                             qw, kw, vw, Who);
    k_attn_out<<<1024, 512, 0, stream>>>(qw, kw, vw, mask, Who, out);
}